// Round 1
// baseline (171.830 us; speedup 1.0000x reference)
//
#include <hip/hip_runtime.h>
#include <cstdint>
#include <cstddef>

typedef _Float16 half_t;
typedef _Float16 half8 __attribute__((ext_vector_type(8)));
typedef float floatx4 __attribute__((ext_vector_type(4)));

#define E_ 8
#define D_ 512
#define H_ 2048
#define NTOK 1024
#define NP 2048          // NTOK * top_k
#define TM 64            // GEMM M-tile (rows)
#define MAX_TILES 40     // 2048/64 + 8 experts

__device__ __forceinline__ float gelu_f(float x) {
    return 0.5f * x * (1.0f + erff(x * 0.7071067811865476f));
}

// async global->LDS, 16 bytes per lane; LDS dest is wave-uniform base + lane*16
__device__ __forceinline__ void gload_lds16(const half_t* g, half_t* l) {
    __builtin_amdgcn_global_load_lds(
        (__attribute__((address_space(1))) void*)(g),
        (__attribute__((address_space(3))) void*)(l),
        16, 0, 0);
}

// ---------------- gate: logits only (no atomics) ----------------
__global__ __launch_bounds__(256) void gate_kernel(
        const float* __restrict__ inp, const float* __restrict__ gate_w,
        const float* __restrict__ gate_b, float* __restrict__ logits) {
    int n = blockIdx.x * 4 + (threadIdx.x >> 6);
    int lane = threadIdx.x & 63;
    const floatx4* xr = (const floatx4*)(inp + (size_t)n * D_);
    floatx4 x0 = xr[lane * 2], x1 = xr[lane * 2 + 1];
    #pragma unroll
    for (int e = 0; e < E_; e++) {
        const floatx4* gr = (const floatx4*)(gate_w + (size_t)e * D_);
        floatx4 g0 = gr[lane * 2], g1 = gr[lane * 2 + 1];
        float p = x0[0]*g0[0] + x0[1]*g0[1] + x0[2]*g0[2] + x0[3]*g0[3]
                + x1[0]*g1[0] + x1[1]*g1[1] + x1[2]*g1[2] + x1[3]*g1[3];
        #pragma unroll
        for (int m = 1; m < 64; m <<= 1) p += __shfl_xor(p, m);
        if (lane == 0) logits[(size_t)n * E_ + e] = p + gate_b[e];
    }
}

// ---------------- plan: single block does top2/softmax/hist/offsets/tiles ----------------
__global__ __launch_bounds__(256) void plan_kernel(
        const float* __restrict__ logits, float* __restrict__ score,
        int* __restrict__ idx, int* __restrict__ pos_of_pair,
        int* __restrict__ tile_e, int* __restrict__ tile_row0,
        int* __restrict__ tile_cnt, int* __restrict__ ntiles) {
    __shared__ int cnt_s[E_], off_s[E_ + 1], cur_s[E_];
    int tid = threadIdx.x;
    if (tid < E_) { cnt_s[tid] = 0; cur_s[tid] = 0; }
    __syncthreads();
    int my_e[4][2];
    #pragma unroll
    for (int i = 0; i < 4; i++) {
        int n = tid + i * 256;
        float l[E_];
        #pragma unroll
        for (int e = 0; e < E_; e++) l[e] = logits[(size_t)n * E_ + e];
        int e0 = 0; float v0 = l[0];
        #pragma unroll
        for (int e = 1; e < E_; e++) if (l[e] > v0) { v0 = l[e]; e0 = e; }
        int e1 = -1; float v1 = -3.4e38f;
        #pragma unroll
        for (int e = 0; e < E_; e++) if (e != e0 && l[e] > v1) { v1 = l[e]; e1 = e; }
        float s1 = expf(v1 - v0);
        float den = 1.0f + s1;
        score[2 * n]     = 1.0f / den;
        score[2 * n + 1] = s1 / den;
        idx[2 * n]     = e0;
        idx[2 * n + 1] = e1;
        atomicAdd(&cnt_s[e0], 1);
        atomicAdd(&cnt_s[e1], 1);
        my_e[i][0] = e0; my_e[i][1] = e1;
    }
    __syncthreads();
    if (tid == 0) {
        int o = 0;
        #pragma unroll
        for (int e = 0; e < E_; e++) { off_s[e] = o; o += cnt_s[e]; }
        off_s[E_] = o;
        int t = 0;
        for (int e = 0; e < E_; e++) {
            int c = cnt_s[e];
            int nt = (c + TM - 1) / TM;
            for (int i = 0; i < nt; i++) {
                tile_e[t] = e;
                tile_row0[t] = off_s[e] + i * TM;
                int rem = c - i * TM;
                tile_cnt[t] = rem < TM ? rem : TM;
                t++;
            }
        }
        ntiles[0] = t;
    }
    __syncthreads();
    #pragma unroll
    for (int i = 0; i < 4; i++) {
        #pragma unroll
        for (int k = 0; k < 2; k++) {
            int p = (tid + i * 256) * 2 + k;
            int e = my_e[i][k];
            int r = atomicAdd(&cur_s[e], 1);
            pos_of_pair[p] = off_s[e] + r;
        }
    }
}

// ---------------- scatter: copy token rows to f16 at grouped positions ----------------
__global__ __launch_bounds__(256) void scatter_kernel(
        const float* __restrict__ inp, const int* __restrict__ pos_of_pair,
        half_t* __restrict__ Xg) {
    int p = blockIdx.x * 4 + (threadIdx.x >> 6);
    int lane = threadIdx.x & 63;
    int pos = pos_of_pair[p];
    int n = p >> 1;
    const floatx4* src = (const floatx4*)(inp + (size_t)n * D_);
    floatx4 f0 = src[lane * 2], f1 = src[lane * 2 + 1];
    half8 h = { (half_t)f0[0], (half_t)f0[1], (half_t)f0[2], (half_t)f0[3],
                (half_t)f1[0], (half_t)f1[1], (half_t)f1[2], (half_t)f1[3] };
    *(half8*)(Xg + (size_t)pos * D_ + lane * 8) = h;
}

// ---------------- fp32 -> f16 weight conversion (both weights, one launch) ----------------
__global__ __launch_bounds__(256) void cvt_kernel(
        const float* __restrict__ w1, const float* __restrict__ w2,
        half_t* __restrict__ W1h, half_t* __restrict__ W2h) {
    const int n8 = E_ * H_ * D_ / 8;   // per-tensor 8-element groups
    int i = blockIdx.x * 256 + threadIdx.x;
    const float* src; half_t* dst; int j;
    if (i < n8) { src = w1; dst = W1h; j = i; }
    else        { src = w2; dst = W2h; j = i - n8; }
    const floatx4* s = (const floatx4*)src + (size_t)j * 2;
    floatx4 f0 = s[0], f1 = s[1];
    half8 h = { (half_t)f0[0], (half_t)f0[1], (half_t)f0[2], (half_t)f0[3],
                (half_t)f1[0], (half_t)f1[1], (half_t)f1[2], (half_t)f1[3] };
    *(half8*)(dst + (size_t)j * 8) = h;
}

// ---------------- GEMM1: Y1 = gelu(Xg @ W1[e]^T + b1[e]) ----------------
// 64x128 tile, BK=64, double-buffered LDS (2-phase pipeline), 4 waves of 32x64
__global__ __launch_bounds__(256) void gemm1_kernel(
        const half_t* __restrict__ Xg, const half_t* __restrict__ W1h,
        const float* __restrict__ b1,
        const int* __restrict__ tile_e, const int* __restrict__ tile_row0,
        const int* __restrict__ tile_cnt, const int* __restrict__ ntiles,
        half_t* __restrict__ Y1) {
    __shared__ half_t As[2][TM * 64];    // 2 x 8 KB
    __shared__ half_t Bs[2][128 * 64];   // 2 x 16 KB
    int t = blockIdx.x;
    if (t >= ntiles[0]) return;
    int e = tile_e[t], row0 = tile_row0[t], cnt = tile_cnt[t];
    int colbase = blockIdx.y * 128;
    int tid = threadIdx.x;
    int wave = tid >> 6, lane = tid & 63;
    int quad = lane >> 4, l16 = lane & 15;
    int wm = (wave & 1) * 32, wn = (wave >> 1) * 64;

    // staging: granule G covers row G>>3, halfs (G&7)*8 .. +8 of the k-slice
    int srow = tid >> 3, skc = (tid & 7) * 8;
    const half_t* Ag0 = Xg + (size_t)(row0 + srow) * D_ + skc;
    const half_t* Ag1 = Ag0 + 32 * D_;
    const half_t* Bg0 = W1h + ((size_t)e * H_ + colbase + srow) * D_ + skc;
    const half_t* Bg1 = Bg0 + 32 * D_;
    const half_t* Bg2 = Bg0 + 64 * D_;
    const half_t* Bg3 = Bg0 + 96 * D_;

    #define STAGE1(buf, k0)                                        \
        do {                                                       \
            gload_lds16(Ag0 + (k0), &As[buf][(size_t)tid * 8]);            \
            gload_lds16(Ag1 + (k0), &As[buf][(size_t)(tid + 256) * 8]);    \
            gload_lds16(Bg0 + (k0), &Bs[buf][(size_t)tid * 8]);            \
            gload_lds16(Bg1 + (k0), &Bs[buf][(size_t)(tid + 256) * 8]);    \
            gload_lds16(Bg2 + (k0), &Bs[buf][(size_t)(tid + 512) * 8]);    \
            gload_lds16(Bg3 + (k0), &Bs[buf][(size_t)(tid + 768) * 8]);    \
        } while (0)

    floatx4 acc[2][4] = {};
    STAGE1(0, 0);
    __syncthreads();
    int cur = 0;
    for (int k0 = 0; k0 < D_; k0 += 64) {
        if (k0 + 64 < D_) STAGE1(cur ^ 1, k0 + 64);
        const half_t* Ab = &As[cur][0];
        const half_t* Bb = &Bs[cur][0];
        #pragma unroll
        for (int ks = 0; ks < 2; ks++) {
            half8 a[2], b[4];
            #pragma unroll
            for (int mi = 0; mi < 2; mi++)
                a[mi] = *(const half8*)(Ab + (wm + mi * 16 + l16) * 64 + ks * 32 + quad * 8);
            #pragma unroll
            for (int ni = 0; ni < 4; ni++)
                b[ni] = *(const half8*)(Bb + (wn + ni * 16 + l16) * 64 + ks * 32 + quad * 8);
            #pragma unroll
            for (int mi = 0; mi < 2; mi++)
                #pragma unroll
                for (int ni = 0; ni < 4; ni++)
                    acc[mi][ni] = __builtin_amdgcn_mfma_f32_16x16x32_f16(a[mi], b[ni], acc[mi][ni], 0, 0, 0);
        }
        __syncthreads();
        cur ^= 1;
    }
    #undef STAGE1

    float bias[4];
    #pragma unroll
    for (int ni = 0; ni < 4; ni++)
        bias[ni] = b1[(size_t)e * H_ + colbase + wn + ni * 16 + l16];
    #pragma unroll
    for (int mi = 0; mi < 2; mi++) {
        #pragma unroll
        for (int r = 0; r < 4; r++) {
            int rr = wm + mi * 16 + quad * 4 + r;
            if (rr >= cnt) continue;
            size_t rowoff = (size_t)(row0 + rr) * H_;
            #pragma unroll
            for (int ni = 0; ni < 4; ni++) {
                float v = acc[mi][ni][r] + bias[ni];
                Y1[rowoff + colbase + wn + ni * 16 + l16] = (half_t)gelu_f(v);
            }
        }
    }
}

// ---------------- GEMM2 (split-K=4): Y2p[kz] = Y1 @ W2[e]^T ----------------
// 64x128 tile, BK=64, double-buffered LDS, 4 waves of 32x64
__global__ __launch_bounds__(256) void gemm2_kernel(
        const half_t* __restrict__ Y1, const half_t* __restrict__ W2h,
        const int* __restrict__ tile_e, const int* __restrict__ tile_row0,
        const int* __restrict__ tile_cnt, const int* __restrict__ ntiles,
        float* __restrict__ Y2p) {
    __shared__ half_t As[2][TM * 64];
    __shared__ half_t Bs[2][128 * 64];
    int t = blockIdx.x;
    if (t >= ntiles[0]) return;
    int e = tile_e[t], row0 = tile_row0[t], cnt = tile_cnt[t];
    int colbase = blockIdx.y * 128;
    int kz = blockIdx.z;
    int kzbase = kz * 512;
    int tid = threadIdx.x;
    int wave = tid >> 6, lane = tid & 63;
    int quad = lane >> 4, l16 = lane & 15;
    int wm = (wave & 1) * 32, wn = (wave >> 1) * 64;

    int srow = tid >> 3, skc = (tid & 7) * 8;
    const half_t* Ag0 = Y1 + (size_t)(row0 + srow) * H_ + kzbase + skc;
    const half_t* Ag1 = Ag0 + 32 * H_;
    const half_t* Bg0 = W2h + ((size_t)e * D_ + colbase + srow) * H_ + kzbase + skc;
    const half_t* Bg1 = Bg0 + 32 * H_;
    const half_t* Bg2 = Bg0 + 64 * H_;
    const half_t* Bg3 = Bg0 + 96 * H_;

    #define STAGE2(buf, k0)                                        \
        do {                                                       \
            gload_lds16(Ag0 + (k0), &As[buf][(size_t)tid * 8]);            \
            gload_lds16(Ag1 + (k0), &As[buf][(size_t)(tid + 256) * 8]);    \
            gload_lds16(Bg0 + (k0), &Bs[buf][(size_t)tid * 8]);            \
            gload_lds16(Bg1 + (k0), &Bs[buf][(size_t)(tid + 256) * 8]);    \
            gload_lds16(Bg2 + (k0), &Bs[buf][(size_t)(tid + 512) * 8]);    \
            gload_lds16(Bg3 + (k0), &Bs[buf][(size_t)(tid + 768) * 8]);    \
        } while (0)

    floatx4 acc[2][4] = {};
    STAGE2(0, 0);
    __syncthreads();
    int cur = 0;
    for (int k0 = 0; k0 < 512; k0 += 64) {
        if (k0 + 64 < 512) STAGE2(cur ^ 1, k0 + 64);
        const half_t* Ab = &As[cur][0];
        const half_t* Bb = &Bs[cur][0];
        #pragma unroll
        for (int ks = 0; ks < 2; ks++) {
            half8 a[2], b[4];
            #pragma unroll
            for (int mi = 0; mi < 2; mi++)
                a[mi] = *(const half8*)(Ab + (wm + mi * 16 + l16) * 64 + ks * 32 + quad * 8);
            #pragma unroll
            for (int ni = 0; ni < 4; ni++)
                b[ni] = *(const half8*)(Bb + (wn + ni * 16 + l16) * 64 + ks * 32 + quad * 8);
            #pragma unroll
            for (int mi = 0; mi < 2; mi++)
                #pragma unroll
                for (int ni = 0; ni < 4; ni++)
                    acc[mi][ni] = __builtin_amdgcn_mfma_f32_16x16x32_f16(a[mi], b[ni], acc[mi][ni], 0, 0, 0);
        }
        __syncthreads();
        cur ^= 1;
    }
    #undef STAGE2

    #pragma unroll
    for (int mi = 0; mi < 2; mi++) {
        #pragma unroll
        for (int r = 0; r < 4; r++) {
            int rr = wm + mi * 16 + quad * 4 + r;
            if (rr >= cnt) continue;
            size_t rowoff = ((size_t)kz * NP + row0 + rr) * D_;
            #pragma unroll
            for (int ni = 0; ni < 4; ni++)
                Y2p[rowoff + colbase + wn + ni * 16 + l16] = acc[mi][ni][r];
        }
    }
}

// ---------------- combine + bias + LayerNorm, wave per token ----------------
__global__ __launch_bounds__(256) void final_kernel(
        const float* __restrict__ Y2p, const float* __restrict__ b2,
        const int* __restrict__ idx, const float* __restrict__ score,
        const int* __restrict__ pos_of_pair,
        const float* __restrict__ ln_w, const float* __restrict__ ln_b,
        float* __restrict__ out) {
    int n = blockIdx.x * 4 + (threadIdx.x >> 6);
    int lane = threadIdx.x & 63;
    int p0 = pos_of_pair[2 * n], p1 = pos_of_pair[2 * n + 1];
    int e0 = idx[2 * n], e1 = idx[2 * n + 1];
    float s0 = score[2 * n], s1 = score[2 * n + 1];

    const floatx4* b2r0 = (const floatx4*)(b2 + (size_t)e0 * D_);
    const floatx4* b2r1 = (const floatx4*)(b2 + (size_t)e1 * D_);
    floatx4 a_lo = b2r0[lane * 2], a_hi = b2r0[lane * 2 + 1];
    floatx4 c_lo = b2r1[lane * 2], c_hi = b2r1[lane * 2 + 1];
    #pragma unroll
    for (int kz = 0; kz < 4; kz++) {
        const floatx4* r0 = (const floatx4*)(Y2p + ((size_t)kz * NP + p0) * D_);
        const floatx4* r1 = (const floatx4*)(Y2p + ((size_t)kz * NP + p1) * D_);
        a_lo += r0[lane * 2]; a_hi += r0[lane * 2 + 1];
        c_lo += r1[lane * 2]; c_hi += r1[lane * 2 + 1];
    }
    floatx4 y_lo = s0 * a_lo + s1 * c_lo;
    floatx4 y_hi = s0 * a_hi + s1 * c_hi;

    float s = 0.0f, q = 0.0f;
    #pragma unroll
    for (int j = 0; j < 4; j++) {
        s += y_lo[j] + y_hi[j];
        q += y_lo[j] * y_lo[j] + y_hi[j] * y_hi[j];
    }
    #pragma unroll
    for (int m = 1; m < 64; m <<= 1) {
        s += __shfl_xor(s, m);
        q += __shfl_xor(q, m);
    }
    float mean = s * (1.0f / 512.0f);
    float var = q * (1.0f / 512.0f) - mean * mean;
    float inv = 1.0f / sqrtf(var + 1e-5f);

    const floatx4* wv = (const floatx4*)ln_w;
    const floatx4* bv = (const floatx4*)ln_b;
    floatx4 o_lo = (y_lo - mean) * inv * wv[lane * 2]     + bv[lane * 2];
    floatx4 o_hi = (y_hi - mean) * inv * wv[lane * 2 + 1] + bv[lane * 2 + 1];
    floatx4* op = (floatx4*)(out + (size_t)n * D_);
    op[lane * 2] = o_lo;
    op[lane * 2 + 1] = o_hi;
}

extern "C" void kernel_launch(void* const* d_in, const int* in_sizes, int n_in,
                              void* d_out, int out_size, void* d_ws, size_t ws_size,
                              hipStream_t stream) {
    const float* inp    = (const float*)d_in[0];
    const float* gate_w = (const float*)d_in[1];
    const float* gate_b = (const float*)d_in[2];
    const float* w1     = (const float*)d_in[3];
    const float* b1     = (const float*)d_in[4];
    const float* w2     = (const float*)d_in[5];
    const float* b2     = (const float*)d_in[6];
    const float* ln_w   = (const float*)d_in[7];
    const float* ln_b   = (const float*)d_in[8];
    float* out = (float*)d_out;

    char* ws = (char*)d_ws;
    size_t o = 0;
    auto carve = [&](size_t bytes) -> char* {
        char* p = ws + o;
        o += (bytes + 255) & ~(size_t)255;
        return p;
    };
    half_t* W1h = (half_t*)carve(sizeof(half_t) * (size_t)E_ * H_ * D_);        // 16 MB
    half_t* W2h = (half_t*)carve(sizeof(half_t) * (size_t)E_ * D_ * H_);        // 16 MB
    half_t* Xg  = (half_t*)carve(sizeof(half_t) * (size_t)(NP + 128) * D_);     // slack for tile overrun
    half_t* Y1  = (half_t*)carve(sizeof(half_t) * (size_t)(NP + 128) * H_);     // slack
    float*  Y2p = (float*)carve(sizeof(float) * 4 * (size_t)NP * D_);           // 16.8 MB
    float*  logits = (float*)carve(sizeof(float) * NTOK * E_);
    float*  score  = (float*)carve(sizeof(float) * NP);
    int* idx         = (int*)carve(sizeof(int) * NP);
    int* pos_of_pair = (int*)carve(sizeof(int) * NP);
    int* tile_e      = (int*)carve(sizeof(int) * MAX_TILES);
    int* tile_row0   = (int*)carve(sizeof(int) * MAX_TILES);
    int* tile_cnt    = (int*)carve(sizeof(int) * MAX_TILES);
    int* ntiles      = (int*)carve(sizeof(int) * 1);

    gate_kernel<<<NTOK / 4, 256, 0, stream>>>(inp, gate_w, gate_b, logits);
    plan_kernel<<<1, 256, 0, stream>>>(logits, score, idx, pos_of_pair,
                                       tile_e, tile_row0, tile_cnt, ntiles);
    scatter_kernel<<<NP / 4, 256, 0, stream>>>(inp, pos_of_pair, Xg);
    cvt_kernel<<<2 * E_ * H_ * D_ / 8 / 256, 256, 0, stream>>>(w1, w2, W1h, W2h);
    gemm1_kernel<<<dim3(MAX_TILES, H_ / 128), 256, 0, stream>>>(
        Xg, W1h, b1, tile_e, tile_row0, tile_cnt, ntiles, Y1);
    gemm2_kernel<<<dim3(MAX_TILES, D_ / 128, 4), 256, 0, stream>>>(
        Y1, W2h, tile_e, tile_row0, tile_cnt, ntiles, Y2p);
    final_kernel<<<NTOK / 4, 256, 0, stream>>>(Y2p, b2, idx, score, pos_of_pair, ln_w, ln_b, out);
}